// Round 1
// baseline (387.521 us; speedup 1.0000x reference)
//
#include <hip/hip_runtime.h>
#include <hip/hip_bf16.h>
#include <float.h>

// AFM: out[b] = sum_f linear_table[idx]+linear_bias + softmax-pooled cross term.
// B=16384 rows, F=24 fields, E=16, A=32, P=276 pairs.
// One block of 320 threads (5 waves) per row; one thread per pair for the
// 16x32 attention MLP (the dominant ~512 FMA/pair). All small tensors staged
// in LDS; emb/inner use stride-17 padding (17 coprime 32 -> conflict-free).

#define FN   24
#define ED   16
#define AS   32
#define NP   276
#define ESTR 17
#define ISTR 17
#define NTHR 320
#define FIELD_SIZE 50000

__device__ __forceinline__ float waveMax(float v) {
#pragma unroll
    for (int off = 32; off > 0; off >>= 1) v = fmaxf(v, __shfl_xor(v, off, 64));
    return v;
}
__device__ __forceinline__ float waveSum(float v) {
#pragma unroll
    for (int off = 32; off > 0; off >>= 1) v += __shfl_xor(v, off, 64);
    return v;
}

__global__ __launch_bounds__(NTHR) void afm_kernel(
    const int*   __restrict__ x,            // [B, F]
    const float* __restrict__ embed_table,  // [V, E]
    const float* __restrict__ linear_table, // [V, 1]
    const float* __restrict__ linear_bias,  // [1]
    const float* __restrict__ attn_W,       // [E, A]
    const float* __restrict__ attn_b,       // [A]
    const float* __restrict__ proj_w,       // [A, 1]
    const float* __restrict__ proj_b,       // [1] (softmax-invariant)
    const float* __restrict__ fc_w,         // [E, 1]
    const float* __restrict__ fc_b,         // [1]
    float*       __restrict__ out)          // [B]
{
    __shared__ float emb_s[FN * ESTR];      // 408
    __shared__ float W_s[ED * AS];          // 512
    __shared__ float ab_s[AS];
    __shared__ float pw_s[AS];
    __shared__ float fw_s[ED];
    __shared__ float inner_s[NP * ISTR];    // 4692 floats ~= 18.3 KB
    __shared__ float sc_s[NP];
    __shared__ float lin_s[FN];
    __shared__ int   idx_s[FN];
    __shared__ float red_s[8];
    __shared__ float part_s[20 * 17];       // 20 groups x 16 (padded)
    __shared__ float red2_s[ED];

    const int b   = blockIdx.x;
    const int tid = threadIdx.x;

    // ---- Phase A: indices, linear gather, weight staging ----
    if (tid < FN) {
        int id = x[b * FN + tid] + tid * FIELD_SIZE;
        idx_s[tid] = id;
        lin_s[tid] = linear_table[id];
    }
    for (int t = tid; t < ED * AS; t += NTHR) W_s[t] = attn_W[t];
    if (tid >= 64 && tid < 64 + AS)  ab_s[tid - 64]  = attn_b[tid - 64];
    if (tid >= 128 && tid < 128 + AS) pw_s[tid - 128] = proj_w[tid - 128];
    if (tid >= 192 && tid < 192 + ED) fw_s[tid - 192] = fc_w[tid - 192];
    __syncthreads();

    // ---- Phase B: embedding gather (float4, 96 loads) ----
    for (int t = tid; t < FN * 4; t += NTHR) {
        int f = t >> 2, q = t & 3;
        const float4 v = ((const float4*)(embed_table + (size_t)idx_s[f] * ED))[q];
        float* dst = &emb_s[f * ESTR + q * 4];
        dst[0] = v.x; dst[1] = v.y; dst[2] = v.z; dst[3] = v.w;
    }
    __syncthreads();

    // ---- Phase D: per-pair inner product + attention MLP score ----
    float inner[ED];
    if (tid < NP) {
        int rem = tid, i = 0;
        while (rem >= FN - 1 - i) { rem -= FN - 1 - i; ++i; }
        const int j = i + 1 + rem;
#pragma unroll
        for (int e = 0; e < ED; ++e)
            inner[e] = emb_s[i * ESTR + e] * emb_s[j * ESTR + e];
#pragma unroll
        for (int e = 0; e < ED; ++e)
            inner_s[tid * ISTR + e] = inner[e];
        float sc = 0.f;
#pragma unroll
        for (int a = 0; a < AS; ++a) {
            float h = ab_s[a];
#pragma unroll
            for (int e = 0; e < ED; ++e) h = fmaf(inner[e], W_s[e * AS + a], h);
            h = fmaxf(h, 0.f);
            sc = fmaf(h, pw_s[a], sc);
        }
        sc_s[tid] = sc;
    }
    __syncthreads();

    // ---- Phase E: softmax over the 276 scores ----
    float v = (tid < NP) ? sc_s[tid] : -FLT_MAX;
    v = waveMax(v);
    if ((tid & 63) == 0) red_s[tid >> 6] = v;
    __syncthreads();
    if (tid == 0) {
        float m = red_s[0];
#pragma unroll
        for (int w = 1; w < NTHR / 64; ++w) m = fmaxf(m, red_s[w]);
        red_s[0] = m;
    }
    __syncthreads();
    const float mx = red_s[0];
    float es = 0.f;
    if (tid < NP) {
        es = __expf(sc_s[tid] - mx);
        sc_s[tid] = es;
    }
    __syncthreads();   // protect red_s[0] read before rewrite
    float s = waveSum(es);
    if ((tid & 63) == 0) red_s[tid >> 6] = s;
    __syncthreads();
    if (tid == 0) {
        float t = 0.f;
#pragma unroll
        for (int w = 0; w < NTHR / 64; ++w) t += red_s[w];
        red_s[1] = 1.f / t;
    }
    __syncthreads();
    const float inv = red_s[1];

    // ---- Phase F: pooled[e] = inv * sum_p es[p]*inner[p][e]; final scalar ----
    {
        const int g = tid >> 4;      // 0..19
        const int e = tid & 15;
        float part = 0.f;
        for (int p = g; p < NP; p += 20)
            part = fmaf(sc_s[p], inner_s[p * ISTR + e], part);
        part_s[g * 17 + e] = part;
    }
    __syncthreads();
    if (tid < ED) {
        float pooled = 0.f;
#pragma unroll
        for (int g = 0; g < 20; ++g) pooled += part_s[g * 17 + tid];
        red2_s[tid] = pooled * inv * fw_s[tid];
    }
    __syncthreads();
    if (tid == 0) {
        float cross = 0.f;
#pragma unroll
        for (int e = 0; e < ED; ++e) cross += red2_s[e];
        float lin = 0.f;
#pragma unroll
        for (int f = 0; f < FN; ++f) lin += lin_s[f];
        out[b] = lin + linear_bias[0] + cross + fc_b[0];
    }
}

extern "C" void kernel_launch(void* const* d_in, const int* in_sizes, int n_in,
                              void* d_out, int out_size, void* d_ws, size_t ws_size,
                              hipStream_t stream) {
    const int*   x            = (const int*)  d_in[0];
    const float* embed_table  = (const float*)d_in[1];
    const float* linear_table = (const float*)d_in[2];
    const float* linear_bias  = (const float*)d_in[3];
    const float* attn_W       = (const float*)d_in[4];
    const float* attn_b       = (const float*)d_in[5];
    const float* proj_w       = (const float*)d_in[6];
    const float* proj_b       = (const float*)d_in[7];
    const float* fc_w         = (const float*)d_in[8];
    const float* fc_b         = (const float*)d_in[9];
    float* out = (float*)d_out;

    const int B = in_sizes[0] / FN;
    afm_kernel<<<B, NTHR, 0, stream>>>(x, embed_table, linear_table, linear_bias,
                                       attn_W, attn_b, proj_w, proj_b, fc_w, fc_b,
                                       out);
}

// Round 2
// 271.911 us; speedup vs baseline: 1.4252x; 1.4252x over previous
//
#include <hip/hip_runtime.h>
#include <float.h>

// AFM, wave-per-row restructure. B rows; F=24 fields, E=16, A=32, P=276 pairs.
// 256-thread blocks = 4 independent waves, one row each, ZERO __syncthreads.
// Each lane owns 5 pair-slots (5*64=320 >= 276). The 16x32 attention MLP reads
// W/b/pw via wave-uniform addresses -> compiler emits s_load (scalar pipe),
// keeping the VALU loop free of LDS traffic (round-1 bottleneck: ds_read of
// W_s gated the FMA loop at ~1.5 cyc/FMA). Softmax + pooled via wave shuffles;
// inner products recomputed from LDS emb (stride 17) instead of stored.

#define FN   24
#define ED   16
#define AS   32
#define NP   276
#define ESTR 17
#define RPB  4
#define NTHR 256
#define FIELD_SIZE 50000

__device__ __forceinline__ float waveMax(float v) {
#pragma unroll
    for (int off = 32; off; off >>= 1) v = fmaxf(v, __shfl_xor(v, off, 64));
    return v;
}
__device__ __forceinline__ float waveSum(float v) {
#pragma unroll
    for (int off = 32; off; off >>= 1) v += __shfl_xor(v, off, 64);
    return v;
}

__global__ __launch_bounds__(NTHR) void afm_kernel(
    const int*   __restrict__ x,            // [B, F]
    const float* __restrict__ embed_table,  // [V, E]
    const float* __restrict__ linear_table, // [V]
    const float* __restrict__ linear_bias,  // [1]
    const float* __restrict__ attn_W,       // [E, A]
    const float* __restrict__ attn_b,       // [A]
    const float* __restrict__ proj_w,       // [A]
    const float* __restrict__ fc_w,         // [E]
    const float* __restrict__ fc_b,         // [1]
    float*       __restrict__ out,          // [B]
    int B)
{
    __shared__ float emb_s[RPB][FN * ESTR];
    const int wave = threadIdx.x >> 6;
    const int lane = threadIdx.x & 63;
    const int row  = blockIdx.x * RPB + wave;
    if (row >= B) return;
    float* emb = emb_s[wave];

    // ---- indices + linear term (lanes 0..23) ----
    int idxv = 0; float linv = 0.f;
    if (lane < FN) {
        idxv = x[row * FN + lane] + lane * FIELD_SIZE;
        linv = linear_table[idxv];
    }
    const float lin = waveSum(linv);

    // ---- embedding gather: 24 rows x 4 float4 = 96 loads over 64 lanes ----
#pragma unroll
    for (int t = lane; t < FN * 4; t += 64) {
        const int f = t >> 2, q = t & 3;
        const int id = __shfl(idxv, f, 64);
        const float4 v = ((const float4*)(embed_table + (size_t)id * ED))[q];
        float* dst = &emb[f * ESTR + q * 4];
        dst[0] = v.x; dst[1] = v.y; dst[2] = v.z; dst[3] = v.w;
    }
    // Same-wave LDS write->read: compiler-inserted lgkmcnt waits order this;
    // no cross-wave sharing of this buffer, so no barrier needed.

    // ---- pass 1: per-pair attention MLP scores ----
    float sc[5]; int ijp[5];
#pragma unroll
    for (int c = 0; c < 5; ++c) {
        const int p = c * 64 + lane;
        const bool act = p < NP;
        const int pc = act ? p : (NP - 1);
        // invert triangular enumeration: q pairs counted from the end
        const int q = (NP - 1) - pc;
        int m = (int)((sqrtf((float)(8 * q + 1)) + 1.0f) * 0.5f);
        if (m * (m + 1) / 2 <= q) ++m;          // float-precision fixups
        if ((m - 1) * m / 2 > q) --m;
        const int i = (FN - 1) - m;
        const int rem = pc - (NP - m * (m + 1) / 2);
        const int j = i + 1 + rem;
        ijp[c] = (i << 8) | j;

        float inner[ED];
#pragma unroll
        for (int e = 0; e < ED; ++e)
            inner[e] = emb[i * ESTR + e] * emb[j * ESTR + e];

        float h[AS];
#pragma unroll
        for (int a = 0; a < AS; ++a) h[a] = attn_b[a];       // s_load (uniform)
#pragma unroll
        for (int e = 0; e < ED; ++e)
#pragma unroll
            for (int a = 0; a < AS; ++a)
                h[a] = fmaf(inner[e], attn_W[e * AS + a], h[a]);  // W via s_load
        float s = 0.f;
#pragma unroll
        for (int a = 0; a < AS; ++a)
            s = fmaf(fmaxf(h[a], 0.f), proj_w[a], s);
        sc[c] = act ? s : -FLT_MAX;
    }

    // ---- softmax over 276 scores, wave-local ----
    float mx = sc[0];
#pragma unroll
    for (int c = 1; c < 5; ++c) mx = fmaxf(mx, sc[c]);
    mx = waveMax(mx);
    float es[5]; float ssum = 0.f;
#pragma unroll
    for (int c = 0; c < 5; ++c) {
        const int p = c * 64 + lane;
        es[c] = (p < NP) ? __expf(sc[c] - mx) : 0.f;
        ssum += es[c];
    }
    const float inv = 1.f / waveSum(ssum);

    // ---- pass 2: pooled[e] = sum_p es * inner[p][e] (inner recomputed) ----
    float acc[ED];
#pragma unroll
    for (int e = 0; e < ED; ++e) acc[e] = 0.f;
#pragma unroll
    for (int c = 0; c < 5; ++c) {
        const int i = ijp[c] >> 8, j = ijp[c] & 255;
        const float w = es[c];   // 0 for padding slots
#pragma unroll
        for (int e = 0; e < ED; ++e)
            acc[e] = fmaf(w, emb[i * ESTR + e] * emb[j * ESTR + e], acc[e]);
    }
#pragma unroll
    for (int off = 32; off; off >>= 1)
#pragma unroll
        for (int e = 0; e < ED; ++e)
            acc[e] += __shfl_xor(acc[e], off, 64);

    if (lane == 0) {
        float cross = 0.f;
#pragma unroll
        for (int e = 0; e < ED; ++e)
            cross = fmaf(acc[e] * inv, fc_w[e], cross);
        out[row] = lin + linear_bias[0] + cross + fc_b[0];
    }
}

extern "C" void kernel_launch(void* const* d_in, const int* in_sizes, int n_in,
                              void* d_out, int out_size, void* d_ws, size_t ws_size,
                              hipStream_t stream) {
    const int*   x            = (const int*)  d_in[0];
    const float* embed_table  = (const float*)d_in[1];
    const float* linear_table = (const float*)d_in[2];
    const float* linear_bias  = (const float*)d_in[3];
    const float* attn_W       = (const float*)d_in[4];
    const float* attn_b       = (const float*)d_in[5];
    // d_in[6] = proj_w, d_in[7] = proj_b (softmax-invariant, unused)
    const float* proj_w       = (const float*)d_in[6];
    const float* fc_w         = (const float*)d_in[8];
    const float* fc_b         = (const float*)d_in[9];
    float* out = (float*)d_out;

    const int B = in_sizes[0] / FN;
    const int grid = (B + RPB - 1) / RPB;
    afm_kernel<<<grid, NTHR, 0, stream>>>(x, embed_table, linear_table,
                                          linear_bias, attn_W, attn_b, proj_w,
                                          fc_w, fc_b, out, B);
}

// Round 3
// 213.852 us; speedup vs baseline: 1.8121x; 1.2715x over previous
//
#include <hip/hip_runtime.h>
#include <hip/hip_bf16.h>
#include <float.h>

// AFM via MFMA. One wave per row. The 16x32 attention MLP runs as
// h^T = W^T (32x16) @ inner^T (16x32) using v_mfma_f32_32x32x16_bf16:
// M=32(=A), K=16(=E), N=32 pairs per tile, 9 tiles covering P=276.
// h^T's C-layout (col=pair, row=a) makes the proj_w reduction a per-lane
// 16-reg loop + one shfl_xor(32) instead of a cross-lane butterfly.
// Only inner/W go through bf16 (values ~1e-3; threshold 2.2e-2). Softmax,
// pooled pass (fp32 recompute from LDS), linear term all fp32.

#define FN 24
#define ED 16
#define AS 32
#define NP 276
#define NT 9            // 32-pair tiles (288 slots, 276 valid)
#define LASTV 20        // valid cols in last tile: 276 - 8*32
#define EPITCH 20       // emb LDS row pitch in words (80 B, 16B-aligned)
#define RPB 4
#define NTHR 256
#define FIELD_SIZE 50000

typedef __attribute__((ext_vector_type(8)))  short bf16x8;
typedef __attribute__((ext_vector_type(16))) float f32x16;

__device__ __forceinline__ short f2bf(float x) {
    union { __hip_bfloat16 h; short s; } u;
    u.h = __float2bfloat16(x);
    return u.s;
}
__device__ __forceinline__ float waveSum64(float v) {
#pragma unroll
    for (int off = 32; off; off >>= 1) v += __shfl_xor(v, off, 64);
    return v;
}

__global__ __launch_bounds__(NTHR) void afm_kernel(
    const int*   __restrict__ x,
    const float* __restrict__ embed_table,
    const float* __restrict__ linear_table,
    const float* __restrict__ linear_bias,
    const float* __restrict__ attn_W,       // [E, A]
    const float* __restrict__ attn_b,       // [A]
    const float* __restrict__ proj_w,       // [A]
    const float* __restrict__ fc_w,         // [E]
    const float* __restrict__ fc_b,
    float*       __restrict__ out,
    int B)
{
    __shared__ float emb_s[RPB][FN * EPITCH];
    const int wave = threadIdx.x >> 6;
    const int lane = threadIdx.x & 63;
    const int row  = blockIdx.x * RPB + wave;
    if (row >= B) return;
    float* emb = emb_s[wave];
    const int half = lane >> 5;      // k-half / e-half
    const int col  = lane & 31;      // pair-in-tile (B n-index, D col)
    const int e0   = half * 8;

    // ---- indices + linear term ----
    int idxv = 0; float linv = 0.f;
    if (lane < FN) {
        idxv = x[row * FN + lane] + lane * FIELD_SIZE;
        linv = linear_table[idxv];
    }
    const float lin = waveSum64(linv);

    // ---- embedding gather -> LDS (row pitch 80 B) ----
#pragma unroll
    for (int t = lane; t < FN * 4; t += 64) {
        const int f = t >> 2, q = t & 3;
        const int id = __shfl(idxv, f, 64);
        const float4 v = ((const float4*)(embed_table + (size_t)id * ED))[q];
        *(float4*)&emb[f * EPITCH + q * 4] = v;
    }

    // ---- per-lane constants ----
    // A-frag: W^T[a=col][k=e0+i] = attn_W[(e0+i)*AS + col]
    bf16x8 aW;
#pragma unroll
    for (int i = 0; i < 8; ++i) aW[i] = f2bf(attn_W[(e0 + i) * AS + col]);
    // D row map: a = (reg&3) + 8*(reg>>2) + 4*half   [m74/m101 verified]
    float b_r[16], pw_r[16];
#pragma unroll
    for (int r = 0; r < 16; ++r) {
        const int a = (r & 3) + 8 * (r >> 2) + 4 * half;
        b_r[r]  = attn_b[a];
        pw_r[r] = proj_w[a];
    }
    float fcw[8];
#pragma unroll
    for (int i = 0; i < 8; ++i) fcw[i] = fc_w[e0 + i];

    // ---- pair (i,j) byte offsets per tile (closed-form, round-2 verified) ----
    int pko[NT];
#pragma unroll
    for (int t = 0; t < NT; ++t) {
        int p = t * 32 + col; if (p > NP - 1) p = NP - 1;
        const int q = (NP - 1) - p;
        int m = (int)((sqrtf((float)(8 * q + 1)) + 1.0f) * 0.5f);
        if (m * (m + 1) / 2 <= q) ++m;
        if ((m - 1) * m / 2 > q) --m;
        const int fi = (FN - 1) - m;
        const int fj = fi + 1 + (p - (NP - m * (m + 1) / 2));
        pko[t] = ((fi * (EPITCH * 4)) << 16) | (fj * (EPITCH * 4));
    }

    // ---- pass 1: scores via MFMA ----
    float sc[NT];
#pragma unroll
    for (int t = 0; t < NT; ++t) {
        const int oi = (pko[t] >> 16) + half * 32;      // byte offsets, 16B-aligned
        const int oj = (pko[t] & 0xffff) + half * 32;
        const float4 xi0 = *(const float4*)((const char*)emb + oi);
        const float4 xi1 = *(const float4*)((const char*)emb + oi + 16);
        const float4 xj0 = *(const float4*)((const char*)emb + oj);
        const float4 xj1 = *(const float4*)((const char*)emb + oj + 16);
        bf16x8 bfr;
        bfr[0] = f2bf(xi0.x * xj0.x); bfr[1] = f2bf(xi0.y * xj0.y);
        bfr[2] = f2bf(xi0.z * xj0.z); bfr[3] = f2bf(xi0.w * xj0.w);
        bfr[4] = f2bf(xi1.x * xj1.x); bfr[5] = f2bf(xi1.y * xj1.y);
        bfr[6] = f2bf(xi1.z * xj1.z); bfr[7] = f2bf(xi1.w * xj1.w);
        f32x16 c;
#pragma unroll
        for (int r = 0; r < 16; ++r) c[r] = 0.f;
        c = __builtin_amdgcn_mfma_f32_32x32x16_bf16(aW, bfr, c, 0, 0, 0);
        float s = 0.f;
#pragma unroll
        for (int r = 0; r < 16; ++r) {
            const float h = c[r] + b_r[r];
            s = fmaf(fmaxf(h, 0.f), pw_r[r], s);
        }
        s += __shfl_xor(s, 32, 64);     // combine the two a-halves
        sc[t] = (t < NT - 1 || col < LASTV) ? s : -FLT_MAX;
    }

    // ---- softmax over 276 scores (values duplicated across wave halves) ----
    float mx = sc[0];
#pragma unroll
    for (int t = 1; t < NT; ++t) mx = fmaxf(mx, sc[t]);
#pragma unroll
    for (int off = 16; off; off >>= 1) mx = fmaxf(mx, __shfl_xor(mx, off, 64));
    float es[NT], ssum = 0.f;
#pragma unroll
    for (int t = 0; t < NT; ++t) {
        const bool valid = (t < NT - 1) || (col < LASTV);
        es[t] = valid ? __expf(sc[t] - mx) : 0.f;
        ssum += es[t];
    }
#pragma unroll
    for (int off = 16; off; off >>= 1) ssum += __shfl_xor(ssum, off, 64);
    const float inv = 1.f / ssum;

    // ---- pass 2: pooled·fc_w, fp32 recompute of inner from LDS ----
    float acc[8];
#pragma unroll
    for (int i = 0; i < 8; ++i) acc[i] = 0.f;
#pragma unroll
    for (int t = 0; t < NT; ++t) {
        const int oi = (pko[t] >> 16) + half * 32;
        const int oj = (pko[t] & 0xffff) + half * 32;
        const float4 xi0 = *(const float4*)((const char*)emb + oi);
        const float4 xi1 = *(const float4*)((const char*)emb + oi + 16);
        const float4 xj0 = *(const float4*)((const char*)emb + oj);
        const float4 xj1 = *(const float4*)((const char*)emb + oj + 16);
        const float w = es[t];          // 0 for padding slots
        acc[0] = fmaf(w, xi0.x * xj0.x, acc[0]);
        acc[1] = fmaf(w, xi0.y * xj0.y, acc[1]);
        acc[2] = fmaf(w, xi0.z * xj0.z, acc[2]);
        acc[3] = fmaf(w, xi0.w * xj0.w, acc[3]);
        acc[4] = fmaf(w, xi1.x * xj1.x, acc[4]);
        acc[5] = fmaf(w, xi1.y * xj1.y, acc[5]);
        acc[6] = fmaf(w, xi1.z * xj1.z, acc[6]);
        acc[7] = fmaf(w, xi1.w * xj1.w, acc[7]);
    }
    float cp = 0.f;
#pragma unroll
    for (int i = 0; i < 8; ++i) cp = fmaf(acc[i], fcw[i], cp);
    const float cross = waveSum64(cp) * inv;   // sums over pairs AND e-halves

    if (lane == 0)
        out[row] = lin + linear_bias[0] + cross + fc_b[0];
}

extern "C" void kernel_launch(void* const* d_in, const int* in_sizes, int n_in,
                              void* d_out, int out_size, void* d_ws, size_t ws_size,
                              hipStream_t stream) {
    const int*   x            = (const int*)  d_in[0];
    const float* embed_table  = (const float*)d_in[1];
    const float* linear_table = (const float*)d_in[2];
    const float* linear_bias  = (const float*)d_in[3];
    const float* attn_W       = (const float*)d_in[4];
    const float* attn_b       = (const float*)d_in[5];
    const float* proj_w       = (const float*)d_in[6];
    // d_in[7] = proj_b (softmax-invariant)
    const float* fc_w         = (const float*)d_in[8];
    const float* fc_b         = (const float*)d_in[9];
    float* out = (float*)d_out;

    const int B = in_sizes[0] / FN;
    const int grid = (B + RPB - 1) / RPB;
    afm_kernel<<<grid, NTHR, 0, stream>>>(x, embed_table, linear_table,
                                          linear_bias, attn_W, attn_b, proj_w,
                                          fc_w, fc_b, out, B);
}

// Round 4
// 145.769 us; speedup vs baseline: 2.6585x; 1.4671x over previous
//
#include <hip/hip_runtime.h>
#include <hip/hip_bf16.h>
#include <float.h>

// AFM via MFMA, single-pass. One wave per row, 4 rows/block.
// Pass-1-only design: per 32-pair tile, one v_mfma_f32_32x32x16_bf16 computes
// h^T = W^T @ inner^T (bias pre-loaded into the accumulator); the pooled
// cross term is folded into pass 1 via g_p = inner_p . fc_w (per-pair scalar),
// so cross = (sum_p es_p * g_p) / (sum_p es_p) and NO second LDS pass exists.
// bf16 conversion by truncation via one v_perm_b32 per 2 floats (error ~1e-5
// vs 2.2e-2 threshold). Pair->field table computed once per block into LDS.

#define FN 24
#define ED 16
#define AS 32
#define NP 276
#define NT 9            // 32-pair tiles (288 slots)
#define LASTV 20        // valid cols in last tile
#define EPITCH 20       // emb LDS row pitch in words (80 B, keeps b128 aligned)
#define RPB 4
#define NTHR 256
#define FIELD_SIZE 50000

typedef __attribute__((ext_vector_type(8)))  short bf16x8;
typedef __attribute__((ext_vector_type(16))) float f32x16;
typedef __attribute__((ext_vector_type(2)))  float f32x2;

union BFR { int i[4]; bf16x8 v; };

__device__ __forceinline__ short f2bf(float x) {
    union { __hip_bfloat16 h; short s; } u;
    u.h = __float2bfloat16(x);
    return u.s;
}
__device__ __forceinline__ float waveSum64(float v) {
#pragma unroll
    for (int off = 32; off; off >>= 1) v += __shfl_xor(v, off, 64);
    return v;
}

__global__ __launch_bounds__(NTHR, 4) void afm_kernel(
    const int*   __restrict__ x,
    const float* __restrict__ embed_table,
    const float* __restrict__ linear_table,
    const float* __restrict__ linear_bias,
    const float* __restrict__ attn_W,       // [E, A]
    const float* __restrict__ attn_b,       // [A]
    const float* __restrict__ proj_w,       // [A]
    const float* __restrict__ fc_w,         // [E]
    const float* __restrict__ fc_b,
    float*       __restrict__ out,
    int B)
{
    __shared__ float emb_s[RPB][FN * EPITCH];
    __shared__ int   pko_s[NT * 32];

    const int tid  = threadIdx.x;
    const int wave = tid >> 6;
    const int lane = tid & 63;
    const int half = lane >> 5;
    const int col  = lane & 31;
    const int e0   = half * 8;
    const int row  = blockIdx.x * RPB + wave;
    const bool active = row < B;
    const int rowc = active ? row : (B - 1);

    // ---- pair table, block-cooperative (identical for every block) ----
    for (int s = tid; s < NT * 32; s += NTHR) {
        const int p = (s < NP) ? s : (NP - 1);
        const int q = (NP - 1) - p;
        int m = (int)((sqrtf((float)(8 * q + 1)) + 1.0f) * 0.5f);
        if (m * (m + 1) / 2 <= q) ++m;
        if ((m - 1) * m / 2 > q) --m;
        const int fi = (FN - 1) - m;
        const int fj = fi + 1 + (p - (NP - m * (m + 1) / 2));
        pko_s[s] = ((fi * (EPITCH * 4)) << 16) | (fj * (EPITCH * 4));
    }

    // ---- indices + linear term ----
    int idxv = 0; float linv = 0.f;
    if (lane < FN) {
        idxv = x[rowc * FN + lane] + lane * FIELD_SIZE;
        linv = linear_table[idxv];
    }
    const float lin = waveSum64(linv);

    // ---- embedding gather -> LDS ----
    float* emb = emb_s[wave];
#pragma unroll
    for (int t = lane; t < FN * 4; t += 64) {
        const int f = t >> 2, q = t & 3;
        const int id = __shfl(idxv, f, 64);
        *(float4*)&emb[f * EPITCH + q * 4] =
            ((const float4*)(embed_table + (size_t)id * ED))[q];
    }

    // ---- per-lane constants (scalar-pipe loads, wave-uniform addrs) ----
    bf16x8 aW;                         // A-frag: W^T[a=col][k=e0+i]
#pragma unroll
    for (int i = 0; i < 8; ++i) aW[i] = f2bf(attn_W[(e0 + i) * AS + col]);
    f32x2 b2[8], pw2[8];               // D rows: a=(r&3)+8*(r>>2)+4*half
#pragma unroll
    for (int r2 = 0; r2 < 8; ++r2) {
        const int r = 2 * r2;
        const int a0 = (r & 3) + 8 * (r >> 2) + 4 * half;  // pairs are a0,a0+1
        b2[r2].x  = attn_b[a0];  b2[r2].y  = attn_b[a0 + 1];
        pw2[r2].x = proj_w[a0];  pw2[r2].y = proj_w[a0 + 1];
    }
    float fcw[8];
#pragma unroll
    for (int i = 0; i < 8; ++i) fcw[i] = fc_w[e0 + i];

    __syncthreads();   // pko_s ready (emb is same-wave, covered anyway)

    // ---- pass 1: scores + per-pair fc-dot g, one MFMA per tile ----
    const char* embb = (const char*)emb + half * 32;
    float sc[NT], g[NT];
#pragma unroll
    for (int t = 0; t < NT; ++t) {
        const int pk = pko_s[t * 32 + col];
        const int oi = pk >> 16;
        const int oj = pk & 0xffff;
        const float4 xi0 = *(const float4*)(embb + oi);
        const float4 xi1 = *(const float4*)(embb + oi + 16);
        const float4 xj0 = *(const float4*)(embb + oj);
        const float4 xj1 = *(const float4*)(embb + oj + 16);
        const float p0 = xi0.x * xj0.x, p1 = xi0.y * xj0.y;
        const float p2 = xi0.z * xj0.z, p3 = xi0.w * xj0.w;
        const float p4 = xi1.x * xj1.x, p5 = xi1.y * xj1.y;
        const float p6 = xi1.z * xj1.z, p7 = xi1.w * xj1.w;
        // g_p (this e-half): dot with fc_w
        float gv = p0 * fcw[0];
        gv = fmaf(p1, fcw[1], gv); gv = fmaf(p2, fcw[2], gv);
        gv = fmaf(p3, fcw[3], gv); gv = fmaf(p4, fcw[4], gv);
        gv = fmaf(p5, fcw[5], gv); gv = fmaf(p6, fcw[6], gv);
        gv = fmaf(p7, fcw[7], gv);
        g[t] = gv;
        // bf16 truncation pack: one v_perm per 2 floats
        BFR u;
        u.i[0] = __builtin_amdgcn_perm(__float_as_int(p1), __float_as_int(p0), 0x07060302);
        u.i[1] = __builtin_amdgcn_perm(__float_as_int(p3), __float_as_int(p2), 0x07060302);
        u.i[2] = __builtin_amdgcn_perm(__float_as_int(p5), __float_as_int(p4), 0x07060302);
        u.i[3] = __builtin_amdgcn_perm(__float_as_int(p7), __float_as_int(p6), 0x07060302);
        // accumulator pre-loaded with bias
        f32x16 c;
#pragma unroll
        for (int r2 = 0; r2 < 8; ++r2) { c[2 * r2] = b2[r2].x; c[2 * r2 + 1] = b2[r2].y; }
        c = __builtin_amdgcn_mfma_f32_32x32x16_bf16(aW, u.v, c, 0, 0, 0);
        // relu + proj dot (packed f32)
        f32x2 sac; sac.x = 0.f; sac.y = 0.f;
        f32x2 z2;  z2.x = 0.f;  z2.y = 0.f;
#pragma unroll
        for (int r2 = 0; r2 < 8; ++r2) {
            f32x2 h; h.x = c[2 * r2]; h.y = c[2 * r2 + 1];
            h = __builtin_elementwise_max(h, z2);
            sac = __builtin_elementwise_fma(h, pw2[r2], sac);
        }
        float s = sac.x + sac.y;
        s += __shfl_xor(s, 32, 64);     // combine the two a-halves
        sc[t] = s;
    }

    // ---- softmax over 276 (scores duplicated across wave halves) ----
    float mx = sc[0];
#pragma unroll
    for (int t = 1; t < NT; ++t) mx = fmaxf(mx, sc[t]);
#pragma unroll
    for (int off = 16; off; off >>= 1) mx = fmaxf(mx, __shfl_xor(mx, off, 64));
    float es[NT], ssum = 0.f;
#pragma unroll
    for (int t = 0; t < NT; ++t) {
        const bool valid = (t < NT - 1) || (col < LASTV);
        es[t] = valid ? __expf(sc[t] - mx) : 0.f;
        ssum += es[t];
    }
#pragma unroll
    for (int off = 16; off; off >>= 1) ssum += __shfl_xor(ssum, off, 64);
    const float inv = 1.f / ssum;

    // ---- cross = inv * sum_p es_p * g_p  (halves+cols via waveSum) ----
    float cp = 0.f;
#pragma unroll
    for (int t = 0; t < NT; ++t) cp = fmaf(es[t], g[t], cp);
    const float cross = waveSum64(cp) * inv;

    if (active && lane == 0)
        out[row] = lin + linear_bias[0] + cross + fc_b[0];
}

extern "C" void kernel_launch(void* const* d_in, const int* in_sizes, int n_in,
                              void* d_out, int out_size, void* d_ws, size_t ws_size,
                              hipStream_t stream) {
    const int*   x            = (const int*)  d_in[0];
    const float* embed_table  = (const float*)d_in[1];
    const float* linear_table = (const float*)d_in[2];
    const float* linear_bias  = (const float*)d_in[3];
    const float* attn_W       = (const float*)d_in[4];
    const float* attn_b       = (const float*)d_in[5];
    const float* proj_w       = (const float*)d_in[6];
    // d_in[7] = proj_b (softmax-invariant)
    const float* fc_w         = (const float*)d_in[8];
    const float* fc_b         = (const float*)d_in[9];
    float* out = (float*)d_out;

    const int B = in_sizes[0] / FN;
    const int grid = (B + RPB - 1) / RPB;
    afm_kernel<<<grid, NTHR, 0, stream>>>(x, embed_table, linear_table,
                                          linear_bias, attn_W, attn_b, proj_w,
                                          fc_w, fc_b, out, B);
}

// Round 5
// 141.512 us; speedup vs baseline: 2.7384x; 1.0301x over previous
//
#include <hip/hip_runtime.h>
#include <hip/hip_bf16.h>
#include <float.h>

// AFM via MFMA, 4-rows-per-wave software pipeline.
// Per 32-pair tile: one v_mfma_f32_32x32x16_bf16 computes h^T = W^T@inner^T
// (bias preloaded in the accumulator); cross term folded into pass 1 via
// g_p = inner_p . fc_w. Online softmax (running m/ssum/gacc) kills the
// sc/g/es register arrays. Each wave owns 4 consecutive rows: x indices all
// loaded in the prologue; row k+1's embedding gather is issued before row k's
// compute (per-wave LDS double buffer, no in-loop barriers) so the ~500+ cyc
// gather latency hides behind MFMA/VALU work. Weights/pair-table loaded once
// per wave (amortized over 4 rows). bf16 by truncation (v_perm), error ~1e-5
// vs 2.2e-2 threshold.

#define FN 24
#define ED 16
#define AS 32
#define NP 276
#define NT 9            // 32-pair tiles (288 slots)
#define LASTV 20        // valid cols in last tile
#define EPITCH 20       // emb LDS row pitch in words (80 B, b128-aligned)
#define RPW 4           // rows per wave
#define NTHR 256
#define FIELD_SIZE 50000

typedef __attribute__((ext_vector_type(8)))  short bf16x8;
typedef __attribute__((ext_vector_type(16))) float f32x16;
typedef __attribute__((ext_vector_type(2)))  float f32x2;

union BFR { int i[4]; bf16x8 v; };

__device__ __forceinline__ short f2bf(float x) {
    union { __hip_bfloat16 h; short s; } u;
    u.h = __float2bfloat16(x);
    return u.s;
}

__device__ __forceinline__ void gather_embed(const float* __restrict__ et,
                                             int idxv, int lane,
                                             float4& a, float4& b) {
    const int f0 = lane >> 2, q0 = lane & 3;
    const int id0 = __shfl(idxv, f0, 64);
    const int id1 = __shfl(idxv, 16 + f0, 64);   // only meaningful for lane<32
    a = ((const float4*)(et + (size_t)id0 * ED))[q0];
    if (lane < 32)
        b = ((const float4*)(et + (size_t)id1 * ED))[q0];
}

__device__ __forceinline__ void write_embed(float* __restrict__ buf, int lane,
                                            const float4& a, const float4& b) {
    const int f0 = lane >> 2, q0 = lane & 3;
    *(float4*)&buf[f0 * EPITCH + q0 * 4] = a;
    if (lane < 32)
        *(float4*)&buf[(16 + f0) * EPITCH + q0 * 4] = b;
}

__global__ __launch_bounds__(NTHR, 4) void afm_kernel(
    const int*   __restrict__ x,
    const float* __restrict__ embed_table,
    const float* __restrict__ linear_table,
    const float* __restrict__ linear_bias,
    const float* __restrict__ attn_W,       // [E, A]
    const float* __restrict__ attn_b,       // [A]
    const float* __restrict__ proj_w,       // [A]
    const float* __restrict__ fc_w,         // [E]
    const float* __restrict__ fc_b,
    float*       __restrict__ out,
    int B)
{
    __shared__ float emb_s[NTHR / 64][2][FN * EPITCH];
    __shared__ int   pko_s[NT * 32];

    const int tid  = threadIdx.x;
    const int wave = tid >> 6;
    const int lane = tid & 63;
    const int half = lane >> 5;
    const int col  = lane & 31;
    const int e0   = half * 8;
    const int w0   = (blockIdx.x * (NTHR / 64) + wave) * RPW;

    // ---- pair table, block-cooperative ----
    for (int s = tid; s < NT * 32; s += NTHR) {
        const int p = (s < NP) ? s : (NP - 1);
        const int q = (NP - 1) - p;
        int m = (int)((sqrtf((float)(8 * q + 1)) + 1.0f) * 0.5f);
        if (m * (m + 1) / 2 <= q) ++m;
        if ((m - 1) * m / 2 > q) --m;
        const int fi = (FN - 1) - m;
        const int fj = fi + 1 + (p - (NP - m * (m + 1) / 2));
        pko_s[s] = ((fi * (EPITCH * 4)) << 16) | (fj * (EPITCH * 4));
    }

    // ---- prologue: issue ALL x loads for this wave's 4 rows ----
    int idxr[RPW];
#pragma unroll
    for (int k = 0; k < RPW; ++k) {
        const int r = w0 + k, rc = (r < B) ? r : (B - 1);
        idxr[k] = (lane < FN) ? (x[rc * FN + lane] + lane * FIELD_SIZE) : 0;
    }

    // ---- per-lane weight constants (once per 4 rows) ----
    bf16x8 aW;                          // A-frag: W^T[a=col][k=e0+i]
#pragma unroll
    for (int i = 0; i < 8; ++i) aW[i] = f2bf(attn_W[(e0 + i) * AS + col]);
    float b16[16], pw16[16];            // D rows: a=(r&3)+8*(r>>2)+4*half
#pragma unroll
    for (int r = 0; r < 16; ++r) {
        const int a = (r & 3) + 8 * (r >> 2) + 4 * half;
        b16[r]  = attn_b[a];
        pw16[r] = proj_w[a];
    }
    float fcw[8];
#pragma unroll
    for (int i = 0; i < 8; ++i) fcw[i] = fc_w[e0 + i];
    const float cbias = linear_bias[0] + fc_b[0];

    // ---- prologue: row 0 gather + LDS write ----
    float linv = (lane < FN) ? linear_table[idxr[0]] : 0.f;
    {
        float4 ga, gb;
        gather_embed(embed_table, idxr[0], lane, ga, gb);
        write_embed(emb_s[wave][0], lane, ga, gb);
    }

    __syncthreads();                    // pko_s ready
    int pk[NT];
#pragma unroll
    for (int t = 0; t < NT; ++t) pk[t] = pko_s[t * 32 + col];

    // ---- main loop over this wave's rows ----
#pragma unroll
    for (int k = 0; k < RPW; ++k) {
        const int row = w0 + k;
        // prefetch row k+1 (emb gather overlaps row-k compute below)
        float4 na, nb; float linn = 0.f;
        if (k + 1 < RPW) {
            linn = (lane < FN) ? linear_table[idxr[k + 1]] : 0.f;
            gather_embed(embed_table, idxr[k + 1], lane, na, nb);
        }

        const char* embb = (const char*)emb_s[wave][k & 1] + half * 32;
        float m = -FLT_MAX, ssum = 0.f, gacc = 0.f;
#pragma unroll
        for (int t = 0; t < NT; ++t) {
            const int oi = pk[t] >> 16;
            const int oj = pk[t] & 0xffff;
            const float4 xi0 = *(const float4*)(embb + oi);
            const float4 xi1 = *(const float4*)(embb + oi + 16);
            const float4 xj0 = *(const float4*)(embb + oj);
            const float4 xj1 = *(const float4*)(embb + oj + 16);
            const float p0 = xi0.x * xj0.x, p1 = xi0.y * xj0.y;
            const float p2 = xi0.z * xj0.z, p3 = xi0.w * xj0.w;
            const float p4 = xi1.x * xj1.x, p5 = xi1.y * xj1.y;
            const float p6 = xi1.z * xj1.z, p7 = xi1.w * xj1.w;
            float gv = p0 * fcw[0];
            gv = fmaf(p1, fcw[1], gv); gv = fmaf(p2, fcw[2], gv);
            gv = fmaf(p3, fcw[3], gv); gv = fmaf(p4, fcw[4], gv);
            gv = fmaf(p5, fcw[5], gv); gv = fmaf(p6, fcw[6], gv);
            gv = fmaf(p7, fcw[7], gv);
            BFR u;
            u.i[0] = __builtin_amdgcn_perm(__float_as_int(p1), __float_as_int(p0), 0x07060302);
            u.i[1] = __builtin_amdgcn_perm(__float_as_int(p3), __float_as_int(p2), 0x07060302);
            u.i[2] = __builtin_amdgcn_perm(__float_as_int(p5), __float_as_int(p4), 0x07060302);
            u.i[3] = __builtin_amdgcn_perm(__float_as_int(p7), __float_as_int(p6), 0x07060302);
            f32x16 c;
#pragma unroll
            for (int r = 0; r < 16; ++r) c[r] = b16[r];
            c = __builtin_amdgcn_mfma_f32_32x32x16_bf16(aW, u.v, c, 0, 0, 0);
            f32x2 sac; sac.x = 0.f; sac.y = 0.f;
            f32x2 z2;  z2.x = 0.f;  z2.y = 0.f;
#pragma unroll
            for (int r2 = 0; r2 < 8; ++r2) {
                f32x2 h; h.x = c[2 * r2]; h.y = c[2 * r2 + 1];
                h = __builtin_elementwise_max(h, z2);
                f32x2 pw; pw.x = pw16[2 * r2]; pw.y = pw16[2 * r2 + 1];
                sac = __builtin_elementwise_fma(h, pw, sac);
            }
            float s = sac.x + sac.y;
            s += __shfl_xor(s, 32, 64);        // combine the two a-halves
            const bool valid = (t < NT - 1) || (col < LASTV);
            s = valid ? s : -FLT_MAX;
            // online softmax update
            const float mn   = fmaxf(m, s);
            const float cold = __expf(m - mn);
            const float e    = __expf(s - mn);
            ssum = fmaf(ssum, cold, e);
            gacc = fmaf(gacc, cold, e * gv);
            m = mn;
        }

        // ---- reductions: max (half), rescale, sums ----
        float M = m;
#pragma unroll
        for (int off = 16; off; off >>= 1) M = fmaxf(M, __shfl_xor(M, off, 64));
        const float rs = __expf(m - M);
        ssum *= rs; gacc *= rs;
#pragma unroll
        for (int off = 16; off; off >>= 1) ssum += __shfl_xor(ssum, off, 64);
#pragma unroll
        for (int off = 32; off; off >>= 1) gacc += __shfl_xor(gacc, off, 64);
        float lin = linv;
#pragma unroll
        for (int off = 32; off; off >>= 1) lin += __shfl_xor(lin, off, 64);

        if (row < B && lane == 0)
            out[row] = lin + cbias + gacc / ssum;

        // stage next row's embeddings into the other buffer
        if (k + 1 < RPW) {
            write_embed(emb_s[wave][(k + 1) & 1], lane, na, nb);
            linv = linn;
        }
    }
}

extern "C" void kernel_launch(void* const* d_in, const int* in_sizes, int n_in,
                              void* d_out, int out_size, void* d_ws, size_t ws_size,
                              hipStream_t stream) {
    const int*   x            = (const int*)  d_in[0];
    const float* embed_table  = (const float*)d_in[1];
    const float* linear_table = (const float*)d_in[2];
    const float* linear_bias  = (const float*)d_in[3];
    const float* attn_W       = (const float*)d_in[4];
    const float* attn_b       = (const float*)d_in[5];
    const float* proj_w       = (const float*)d_in[6];
    // d_in[7] = proj_b (softmax-invariant)
    const float* fc_w         = (const float*)d_in[8];
    const float* fc_b         = (const float*)d_in[9];
    float* out = (float*)d_out;

    const int B = in_sizes[0] / FN;
    const int rows_per_block = (NTHR / 64) * RPW;   // 16
    const int grid = (B + rows_per_block - 1) / rows_per_block;
    afm_kernel<<<grid, NTHR, 0, stream>>>(x, embed_table, linear_table,
                                          linear_bias, attn_W, attn_b, proj_w,
                                          fc_w, fc_b, out, B);
}